// Round 6
// baseline (76.996 us; speedup 1.0000x reference)
//
#include <hip/hip_runtime.h>

// Quantum circuit collapses analytically:
//   <Z_q> = prod_{j<=q} cos(alpha_j) * cos(beta_j)
// where alpha_j = (x @ W^T)[:,3j] + b[3j], beta_j = (x @ W^T)[:,3j+1] + b[3j+1].
// (CNOT chain conjugates Z_q -> Z_0..Z_q; pre-CNOT state is a product state;
//  RZ phase cancels in |.|^2.)

#define NQ    12
#define NDOT  24      // 2 dots (alpha, beta) per qubit
#define KDIM  512
#define ROWS_PER_BLOCK 16

__global__ __launch_bounds__(256) void qgate_kernel(
    const float* __restrict__ x,   // (8192, 512)
    const float* __restrict__ W,   // (36, 512)
    const float* __restrict__ b,   // (36,)
    float* __restrict__ out)       // (8192, 12)
{
    // Stage the 24 needed W rows (3j, 3j+1) into LDS: 24 x 512 f32 = 48 KB
    __shared__ float4 wlds[NDOT * 128];

    const int tid = threadIdx.x;
    for (int i = tid; i < NDOT * 128; i += 256) {
        const int d  = i >> 7;          // 0..23
        const int kk = i & 127;         // float4 index within row
        const int r  = (d >> 1) * 3 + (d & 1);   // source row in W
        wlds[i] = reinterpret_cast<const float4*>(W)[r * 128 + kk];
    }
    __syncthreads();

    // 16-lane group per batch row: lane l covers k4 = c*16 + l, c = 0..7
    const int l   = tid & 15;
    const int row = blockIdx.x * ROWS_PER_BLOCK + (tid >> 4);

    const float4* __restrict__ xp =
        reinterpret_cast<const float4*>(x + (size_t)row * KDIM);

    // issue all 8 coalesced float4 x-loads up front (memory ILP)
    float4 xv[8];
#pragma unroll
    for (int c = 0; c < 8; ++c) xv[c] = xp[c * 16 + l];

    float2 acc[NDOT];
#pragma unroll
    for (int d = 0; d < NDOT; ++d) acc[d] = make_float2(0.f, 0.f);

#pragma unroll
    for (int c = 0; c < 8; ++c) {
#pragma unroll
        for (int d = 0; d < NDOT; ++d) {
            const float4 wv = wlds[d * 128 + c * 16 + l];
            acc[d].x = fmaf(xv[c].x, wv.x, acc[d].x);
            acc[d].y = fmaf(xv[c].y, wv.y, acc[d].y);
            acc[d].x = fmaf(xv[c].z, wv.z, acc[d].x);
            acc[d].y = fmaf(xv[c].w, wv.w, acc[d].y);
        }
    }

    // butterfly reduce across the 16-lane group (masks < 16 stay in-group)
    float s[NDOT];
#pragma unroll
    for (int d = 0; d < NDOT; ++d) {
        float v = acc[d].x + acc[d].y;
        v += __shfl_xor(v, 1);
        v += __shfl_xor(v, 2);
        v += __shfl_xor(v, 4);
        v += __shfl_xor(v, 8);
        s[d] = v;   // every lane now holds the full dot products
    }

    // epilogue: lane j (< 12) computes z_j, then prefix product over lanes
    const int j = (l < NQ) ? l : (NQ - 1);
    const float aj = s[2 * j]     + b[3 * j];
    const float bj = s[2 * j + 1] + b[3 * j + 1];
    float p = __cosf(aj) * __cosf(bj);

#pragma unroll
    for (int st = 1; st < 16; st <<= 1) {
        const float t = __shfl_up(p, st, 16);   // segmented in 16-lane groups
        if (l >= st) p *= t;
    }

    if (l < NQ) out[(size_t)row * NQ + l] = p;
}

extern "C" void kernel_launch(void* const* d_in, const int* in_sizes, int n_in,
                              void* d_out, int out_size, void* d_ws, size_t ws_size,
                              hipStream_t stream) {
    const float* x = (const float*)d_in[0];   // (8192, 512) f32
    const float* W = (const float*)d_in[1];   // (36, 512)  f32
    const float* b = (const float*)d_in[2];   // (36,)      f32
    float* out     = (float*)d_out;           // (8192, 12) f32

    const int batch = in_sizes[0] / KDIM;     // 8192
    const int grid  = batch / ROWS_PER_BLOCK; // 512
    qgate_kernel<<<grid, 256, 0, stream>>>(x, W, b, out);
}

// Round 9
// 74.014 us; speedup vs baseline: 1.0403x; 1.0403x over previous
//
#include <hip/hip_runtime.h>

// <Z_q> = prod_{j<=q} cos(alpha_j)*cos(beta_j);  (alpha_j,beta_j) = rows 3j,3j+1 of x@W^T+b.
// CNOT chain -> Z-string observable on a product state; RZ cancels.
//
// Layout: 256 thr/block = 8 groups of 32 lanes; each group computes 2 batch rows
// (one LDS W-fragment read feeds both rows -> halves LDS traffic).
// Epilogue: reduce-scatter butterfly with STATIC register indices (no scratch):
// after masks 16,8,4,2,1, lane j of each 16-lane half holds dot sums {2j, 2j+1}.

#define NQ    12
#define NDOT  24
#define KDIM  512
#define ROWS_PER_BLOCK 16   // 8 groups * 2 rows

__global__ __launch_bounds__(256, 2) void qgate_kernel(
    const float* __restrict__ x,   // (8192, 512)
    const float* __restrict__ W,   // (36, 512)
    const float* __restrict__ b,   // (36,)
    float* __restrict__ out)       // (8192, 12)
{
    __shared__ float4 wlds[NDOT * 128];   // 24 rows (3j,3j+1) of W, 48 KB

    const int tid = threadIdx.x;
    for (int i = tid; i < NDOT * 128; i += 256) {
        const int d  = i >> 7;                  // 0..23
        const int kk = i & 127;                 // float4 within row
        const int r  = (d >> 1) * 3 + (d & 1);  // source row of W
        wlds[i] = reinterpret_cast<const float4*>(W)[r * 128 + kk];
    }
    __syncthreads();

    const int l    = tid & 31;   // lane in 32-lane group
    const int g    = tid >> 5;   // group 0..7
    const int row0 = blockIdx.x * ROWS_PER_BLOCK + g * 2;

    const float4* __restrict__ xp0 =
        reinterpret_cast<const float4*>(x + (size_t)row0 * KDIM);
    const float4* __restrict__ xp1 =
        reinterpret_cast<const float4*>(x + (size_t)(row0 + 1) * KDIM);

    float4 xv0[4], xv1[4];
#pragma unroll
    for (int c = 0; c < 4; ++c) { xv0[c] = xp0[c * 32 + l]; xv1[c] = xp1[c * 32 + l]; }

    float2 a0[NDOT], a1[NDOT];
#pragma unroll
    for (int d = 0; d < NDOT; ++d) {
        a0[d] = make_float2(0.f, 0.f);
        a1[d] = make_float2(0.f, 0.f);
    }

#pragma unroll
    for (int c = 0; c < 4; ++c) {
#pragma unroll
        for (int d = 0; d < NDOT; ++d) {
            const float4 wv = wlds[d * 128 + c * 32 + l];   // one read, two rows
            a0[d].x = fmaf(xv0[c].x, wv.x, a0[d].x);
            a0[d].y = fmaf(xv0[c].y, wv.y, a0[d].y);
            a0[d].x = fmaf(xv0[c].z, wv.z, a0[d].x);
            a0[d].y = fmaf(xv0[c].w, wv.w, a0[d].y);
            a1[d].x = fmaf(xv1[c].x, wv.x, a1[d].x);
            a1[d].y = fmaf(xv1[c].y, wv.y, a1[d].y);
            a1[d].x = fmaf(xv1[c].z, wv.z, a1[d].x);
            a1[d].y = fmaf(xv1[c].w, wv.w, a1[d].y);
        }
    }

    // --- mask-16 stage: lanes 0-15 accumulate row0, lanes 16-31 row1 ---
    const bool hi = (l & 16) != 0;
    float v[32];
#pragma unroll
    for (int d = 0; d < NDOT; ++d) {
        const float s0d = a0[d].x + a0[d].y;
        const float s1d = a1[d].x + a1[d].y;
        const float mine  = hi ? s1d : s0d;
        const float send  = hi ? s0d : s1d;
        v[d] = mine + __shfl_xor(send, 16);
    }
#pragma unroll
    for (int d = NDOT; d < 32; ++d) v[d] = 0.f;   // pad dots 24..31

    // --- reduce-scatter: masks 8,4,2,1; all register indices static ---
    float u16[16];
#pragma unroll
    for (int i = 0; i < 16; ++i) {
        const float keep = (l & 8) ? v[16 + i] : v[i];
        const float send = (l & 8) ? v[i] : v[16 + i];
        u16[i] = keep + __shfl_xor(send, 8);
    }
    float u8[8];
#pragma unroll
    for (int i = 0; i < 8; ++i) {
        const float keep = (l & 4) ? u16[8 + i] : u16[i];
        const float send = (l & 4) ? u16[i] : u16[8 + i];
        u8[i] = keep + __shfl_xor(send, 4);
    }
    float u4[4];
#pragma unroll
    for (int i = 0; i < 4; ++i) {
        const float keep = (l & 2) ? u8[4 + i] : u8[i];
        const float send = (l & 2) ? u8[i] : u8[4 + i];
        u4[i] = keep + __shfl_xor(send, 2);
    }
    float u2[2];
#pragma unroll
    for (int i = 0; i < 2; ++i) {
        const float keep = (l & 1) ? u4[2 + i] : u4[i];
        const float send = (l & 1) ? u4[i] : u4[2 + i];
        u2[i] = keep + __shfl_xor(send, 1);
    }
    // lane j = l&15 now holds full dot sums {2j, 2j+1} for its row

    const int j  = l & 15;
    const int jc = (j < NQ) ? j : NQ - 1;       // clamp: keep b[] reads in bounds
    const float aj = u2[0] + b[3 * jc];
    const float bj = u2[1] + b[3 * jc + 1];
    float p = __cosf(aj) * __cosf(bj);

#pragma unroll
    for (int st = 1; st < 16; st <<= 1) {       // prefix product over qubits
        const float t = __shfl_up(p, st, 16);   // segmented within 16-lane half
        if (j >= st) p *= t;
    }

    if (j < NQ) out[(size_t)(row0 + (hi ? 1 : 0)) * NQ + j] = p;
}

extern "C" void kernel_launch(void* const* d_in, const int* in_sizes, int n_in,
                              void* d_out, int out_size, void* d_ws, size_t ws_size,
                              hipStream_t stream) {
    const float* x = (const float*)d_in[0];   // (8192, 512) f32
    const float* W = (const float*)d_in[1];   // (36, 512)  f32
    const float* b = (const float*)d_in[2];   // (36,)      f32
    float* out     = (float*)d_out;           // (8192, 12) f32

    const int batch = in_sizes[0] / KDIM;     // 8192
    const int grid  = batch / ROWS_PER_BLOCK; // 512
    qgate_kernel<<<grid, 256, 0, stream>>>(x, W, b, out);
}